// Round 3
// baseline (41.643 us; speedup 1.0000x reference)
//
#include <hip/hip_runtime.h>
#include <math.h>

typedef __attribute__((ext_vector_type(8))) short short8;
typedef __attribute__((ext_vector_type(4))) float f32x4;

#define NPX 8192
#define NPATCH 8192
#define SPLITS 32
#define TILES_PER_SPLIT 16   // (8192/16)/SPLITS
#define WPB 4                // waves per block
#define PXB 32               // pixel-blocks (8192 / (WPB*64))

__device__ __forceinline__ float fexp2(float x) {
#if __has_builtin(__builtin_amdgcn_exp2f)
    return __builtin_amdgcn_exp2f(x);
#else
    return exp2f(x);
#endif
}

__device__ __forceinline__ unsigned short f2bf(float f) {
    unsigned u = __float_as_uint(f);
    u = u + 0x7FFFu + ((u >> 16) & 1u);
    return (unsigned short)(u >> 16);
}
__device__ __forceinline__ float bf2f(unsigned short h) {
    return __uint_as_float(((unsigned)h) << 16);
}

// ---- prep: build MFMA fragment-ordered hi/lo bf16 records for patches & pixels
__global__ void __launch_bounds__(256) prep(const float* __restrict__ x,
                          const float* __restrict__ patches,
                          const float* __restrict__ t,
                          float* __restrict__ gAh, float* __restrict__ gAl,
                          float* __restrict__ gBh, float* __restrict__ gBl,
                          float* __restrict__ gCent) {
    int id = blockIdx.x * 256 + threadIdx.x;
    float bt2 = t[0];
    float at = sqrtf(1.0f - bt2);
    const float L2E = 1.4426950408889634f;
    if (id < NPATCH) {
        int p = id;
        const float* src = patches + p * 27;
        float v[27]; float pn = 0.f;
#pragma unroll
        for (int k = 0; k < 27; k++) { v[k] = src[k]; pn += v[k] * v[k]; }
        float A2 = at * L2E / bt2;                       // logit slope, log2 units
        float B2 = -at * at * pn * L2E / (2.0f * bt2);   // bias, log2 units
        float sv[28];
#pragma unroll
        for (int k = 0; k < 27; k++) sv[k] = A2 * v[k];
        sv[27] = B2;
        int j = p >> 4, pi = p & 15;
        short8* Ah8 = (short8*)gAh; short8* Al8 = (short8*)gAl;
#pragma unroll
        for (int c = 0; c < 4; c++) {
            short8 H, L;
#pragma unroll
            for (int i = 0; i < 8; i++) {
                int k = c * 8 + i;
                unsigned short hb = 0, lb = 0;
                if (k < 28) { hb = f2bf(sv[k]); lb = f2bf(sv[k] - bf2f(hb)); }
                H[i] = (short)hb; L[i] = (short)lb;
            }
            Ah8[j * 64 + c * 16 + pi] = H;
            Al8[j * 64 + c * 16 + pi] = L;
        }
        gCent[j * 48 + 0  + pi] = v[4];
        gCent[j * 48 + 16 + pi] = v[13];
        gCent[j * 48 + 32 + pi] = v[22];
    } else {
        int px = id - NPATCH;
        int b = px >> 10, rem = px & 1023, h = rem >> 5, w = rem & 31;
        float xv[28];
#pragma unroll
        for (int c3 = 0; c3 < 3; c3++)
#pragma unroll
        for (int dr = 0; dr < 3; dr++)
#pragma unroll
        for (int dc = 0; dc < 3; dc++) {
            int hh = h + dr - 1, ww = w + dc - 1;
            float val = 0.f;
            if ((unsigned)hh < 32u && (unsigned)ww < 32u)
                val = x[b * 3072 + c3 * 1024 + hh * 32 + ww];
            xv[c3 * 9 + dr * 3 + dc] = val;
        }
        xv[27] = 1.0f;
        int wv = px >> 4, pi = px & 15;
        short8* Bh8 = (short8*)gBh; short8* Bl8 = (short8*)gBl;
#pragma unroll
        for (int c = 0; c < 4; c++) {
            short8 H, L;
#pragma unroll
            for (int i = 0; i < 8; i++) {
                int k = c * 8 + i;
                unsigned short hb = 0, lb = 0;
                if (k < 28) { hb = f2bf(xv[k]); lb = f2bf(xv[k] - bf2f(hb)); }
                H[i] = (short)hb; L[i] = (short)lb;
            }
            Bh8[wv * 64 + c * 16 + pi] = H;
            Bl8[wv * 64 + c * 16 + pi] = L;
        }
    }
}

// ---- main: MFMA logits + online softmax; each wave owns 64 pixels (4 groups)
__global__ void __launch_bounds__(256, 4) main_mfma(
        const float* __restrict__ gAh, const float* __restrict__ gAl,
        const float* __restrict__ gBh, const float* __restrict__ gBl,
        const float* __restrict__ gCent,
        float* __restrict__ pm, float* __restrict__ ps,
        float* __restrict__ pc0, float* __restrict__ pc1, float* __restrict__ pc2) {
    __shared__ short8 sAh[TILES_PER_SPLIT * 64];   // 16 KB
    __shared__ short8 sAl[TILES_PER_SPLIT * 64];   // 16 KB
    __shared__ float  sCent[TILES_PER_SPLIT * 48]; // 3 KB
    const int tid = threadIdx.x;
    const int lane = tid & 63, wid = tid >> 6;
    const int split = blockIdx.x, pxb = blockIdx.y;
    const int tb = split * TILES_PER_SPLIT;

    // stage this split's A records (one shot)
    {
        const float4* srcA = (const float4*)gAh + tb * 64;
        const float4* srcL = (const float4*)gAl + tb * 64;
        float4* dA = (float4*)sAh; float4* dL = (float4*)sAl;
#pragma unroll
        for (int i = 0; i < 4; i++) {
            dA[tid + i * 256] = srcA[tid + i * 256];
            dL[tid + i * 256] = srcL[tid + i * 256];
        }
        if (tid < 192) ((float4*)sCent)[tid] = ((const float4*)gCent)[tb * 12 + tid];
    }

    // loop-invariant pixel fragments: 4 groups of 16 pixels
    const int pxg0 = (pxb * WPB + wid) * 4;
    short8 bh[4], bl[4];
#pragma unroll
    for (int j = 0; j < 4; j++) {
        bh[j] = ((const short8*)gBh)[(pxg0 + j) * 64 + lane];
        bl[j] = ((const short8*)gBl)[(pxg0 + j) * 64 + lane];
    }
    __syncthreads();

    float m[4], s[4], a0[4], a1[4], a2[4];
#pragma unroll
    for (int j = 0; j < 4; j++) { m[j] = -1e30f; s[j] = 0.f; a0[j] = 0.f; a1[j] = 0.f; a2[j] = 0.f; }

    const int g = lane >> 4;
    for (int tt = 0; tt < TILES_PER_SPLIT; tt++) {
        short8 ah = sAh[tt * 64 + lane];
        short8 al = sAl[tt * 64 + lane];
        f32x4 d[4];
#pragma unroll
        for (int j = 0; j < 4; j++) {
            f32x4 acc = {0.f, 0.f, 0.f, 0.f};
            acc = __builtin_amdgcn_mfma_f32_16x16x32_bf16(al, bh[j], acc, 0, 0, 0);
            acc = __builtin_amdgcn_mfma_f32_16x16x32_bf16(ah, bl[j], acc, 0, 0, 0);
            acc = __builtin_amdgcn_mfma_f32_16x16x32_bf16(ah, bh[j], acc, 0, 0, 0);
            d[j] = acc;
        }
        float tm[4]; bool act[4]; bool anyact = false;
#pragma unroll
        for (int j = 0; j < 4; j++) {
            tm[j] = fmaxf(fmaxf(d[j].x, d[j].y), fmaxf(d[j].z, d[j].w));
            act[j] = __any(tm[j] > m[j] - 30.0f);
            anyact |= act[j];
        }
        if (anyact) {
            const float4 c0 = ((const float4*)sCent)[tt * 12 + 0 + g];
            const float4 c1 = ((const float4*)sCent)[tt * 12 + 4 + g];
            const float4 c2 = ((const float4*)sCent)[tt * 12 + 8 + g];
#pragma unroll
            for (int j = 0; j < 4; j++) {
                if (act[j]) {
                    if (__any(tm[j] > m[j] + 8.0f)) {   // defer-max rescale
                        float mn = fmaxf(m[j], tm[j]);
                        float sc = fexp2(m[j] - mn);
                        s[j] *= sc; a0[j] *= sc; a1[j] *= sc; a2[j] *= sc; m[j] = mn;
                    }
                    float e0 = fexp2(d[j].x - m[j]);
                    float e1 = fexp2(d[j].y - m[j]);
                    float e2 = fexp2(d[j].z - m[j]);
                    float e3 = fexp2(d[j].w - m[j]);
                    s[j] += (e0 + e1) + (e2 + e3);
                    a0[j] = fmaf(e0, c0.x, fmaf(e1, c0.y, fmaf(e2, c0.z, fmaf(e3, c0.w, a0[j]))));
                    a1[j] = fmaf(e0, c1.x, fmaf(e1, c1.y, fmaf(e2, c1.z, fmaf(e3, c1.w, a1[j]))));
                    a2[j] = fmaf(e0, c2.x, fmaf(e1, c2.y, fmaf(e2, c2.z, fmaf(e3, c2.w, a2[j]))));
                }
            }
        }
    }

    // merge the 4 lane-groups (patch sub-rows) sharing each pixel
#pragma unroll
    for (int j = 0; j < 4; j++) {
#pragma unroll
        for (int off = 16; off <= 32; off <<= 1) {
            float mo = __shfl_xor(m[j], off);
            float so = __shfl_xor(s[j], off);
            float b0 = __shfl_xor(a0[j], off);
            float b1 = __shfl_xor(a1[j], off);
            float b2 = __shfl_xor(a2[j], off);
            float mn = fmaxf(m[j], mo);
            float w1 = fexp2(m[j] - mn), w2 = fexp2(mo - mn);
            s[j]  = s[j]  * w1 + so * w2;
            a0[j] = a0[j] * w1 + b0 * w2;
            a1[j] = a1[j] * w1 + b1 * w2;
            a2[j] = a2[j] * w1 + b2 * w2;
            m[j] = mn;
        }
    }
    // lane writes pixel (lane&15) of group (lane>>4): one coalesced store per array
    float M  = (g == 0) ? m[0]  : (g == 1) ? m[1]  : (g == 2) ? m[2]  : m[3];
    float S  = (g == 0) ? s[0]  : (g == 1) ? s[1]  : (g == 2) ? s[2]  : s[3];
    float A0 = (g == 0) ? a0[0] : (g == 1) ? a0[1] : (g == 2) ? a0[2] : a0[3];
    float A1 = (g == 0) ? a1[0] : (g == 1) ? a1[1] : (g == 2) ? a1[2] : a1[3];
    float A2v= (g == 0) ? a2[0] : (g == 1) ? a2[1] : (g == 2) ? a2[2] : a2[3];
    int o = split * NPX + pxg0 * 16 + lane;
    pm[o] = M; ps[o] = S; pc0[o] = A0; pc1[o] = A1; pc2[o] = A2v;
}

// ---- combine partials + write output ----
__global__ void __launch_bounds__(256) combine(const float* __restrict__ x, const float* __restrict__ t,
                        const float* __restrict__ pm, const float* __restrict__ ps,
                        const float* __restrict__ pc0, const float* __restrict__ pc1,
                        const float* __restrict__ pc2, float* __restrict__ out) {
    int px = blockIdx.x * blockDim.x + threadIdx.x;
    if (px >= NPX) return;
    float M = -1e30f, S = 0.0f, C0 = 0.0f, C1 = 0.0f, C2 = 0.0f;
#pragma unroll 8
    for (int sp = 0; sp < SPLITS; sp++) {
        int o = sp * NPX + px;
        float mi = pm[o];
        float Mn = fmaxf(M, mi);
        float al = fexp2(M - Mn);
        float be = fexp2(mi - Mn);
        S  = S  * al + ps[o]  * be;
        C0 = C0 * al + pc0[o] * be;
        C1 = C1 * al + pc1[o] * be;
        C2 = C2 * al + pc2[o] * be;
        M = Mn;
    }
    float bt2 = t[0];
    float at = sqrtf(1.0f - bt2);
    float invS = 1.0f / S;
    float ibt = 1.0f / bt2;
    int b = px >> 10, rem = px & 1023, h = rem >> 5, w = rem & 31;
    int xi = b * 3072 + h * 32 + w;
    out[xi]        = (at * C0 * invS - x[xi]) * ibt;
    out[xi + 1024] = (at * C1 * invS - x[xi + 1024]) * ibt;
    out[xi + 2048] = (at * C2 * invS - x[xi + 2048]) * ibt;
}

extern "C" void kernel_launch(void* const* d_in, const int* in_sizes, int n_in,
                              void* d_out, int out_size, void* d_ws, size_t ws_size,
                              hipStream_t stream) {
    const float* x = (const float*)d_in[0];
    const float* patches = (const float*)d_in[1];
    const float* t = (const float*)d_in[2];
    float* out = (float*)d_out;
    float* ws = (float*)d_ws;

    float* gAh   = ws;                    // 131072 floats
    float* gAl   = ws + 131072;
    float* gBh   = ws + 262144;
    float* gBl   = ws + 393216;
    float* gCent = ws + 524288;           // 24576 floats
    float* pm    = ws + 548864;           // SPLITS*NPX each
    float* ps    = pm + SPLITS * NPX;
    float* pc0   = ps + SPLITS * NPX;
    float* pc1   = pc0 + SPLITS * NPX;
    float* pc2   = pc1 + SPLITS * NPX;

    hipLaunchKernelGGL(prep, dim3(64), dim3(256), 0, stream,
                       x, patches, t, gAh, gAl, gBh, gBl, gCent);
    hipLaunchKernelGGL(main_mfma, dim3(SPLITS, PXB), dim3(WPB * 64), 0, stream,
                       gAh, gAl, gBh, gBl, gCent, pm, ps, pc0, pc1, pc2);
    hipLaunchKernelGGL(combine, dim3(NPX / 256), dim3(256), 0, stream,
                       x, t, pm, ps, pc0, pc1, pc2, out);
}